// Round 14
// baseline (308.070 us; speedup 1.0000x reference)
//
#include <hip/hip_runtime.h>
#include <hip/hip_bf16.h>

#define NLB 4096
#define NULB 6144
#define NROWS 16384   // 4096 + 2*6144
#define DD 128
#define NC 10
#define VW 12                // P12 row width: 10 numerators + denom + pad
#define SEG 32
#define JSEG (NROWS / SEG)   // 512
#define BI 256               // i-rows per block (4 waves x 64)
#define BJ 64                // j-rows per LDS tile (double-buffered)
#define SQRTC 1.6986437f     // sqrt(2*log2(e))
// F stored as fp8 of (16*SQRTC*f)  ->  QK result cfr = 256 * C * dot
#define FE_BIAS  1.06498747e9f   // f32 fallback bias

typedef __bf16 bf16_t;
typedef _Float16 f16_t;
typedef f16_t f16x8 __attribute__((ext_vector_type(8)));
typedef float f32x4 __attribute__((ext_vector_type(4)));
typedef short i16x2 __attribute__((ext_vector_type(2)));
typedef int i32x8 __attribute__((ext_vector_type(8)));
typedef unsigned int u32;
typedef unsigned char u8;

// fp8 F global layout = swizzled LDS image, 128-row tiles of 128-byte rows:
//   byte address(row, 16B-chunk c0..7) =
//     (row>>7)*16384 + (row&127)*128 + ((c ^ (row&7)) << 4)
// 64-row aligned sub-tiles are contiguous 8 KB spans -> BJ=64 staging works.
__device__ __forceinline__ size_t f8idx(int row, int c) {
  return ((size_t)(row >> 7) << 14) + (size_t)((row & 127) << 7)
       + (size_t)(((c ^ (row & 7)) & 7) << 4);
}

// pack two f16(2^(c/256)) into one dword (fma + pknorm per pair).
// f16 bits of 2^x ~= round(1024x + 15315.35); x = c/256 -> 4*c.
// pknorm: i16 = round(y*32767) -> y = c*(4/32767) + 15315.35/32767.
// staircase rel err ~0.2%, mean-zero, common-mode num/denom.
__device__ __forceinline__ u32 packexp2f16(float c0, float c1) {
#if __has_builtin(__builtin_amdgcn_cvt_pknorm_i16)
  float y0 = fmaf(c0, 1.2207465e-4f, 0.46740490f);
  float y1 = fmaf(c1, 1.2207465e-4f, 0.46740490f);
  union { i16x2 p; u32 u; } cv;
  cv.p = __builtin_amdgcn_cvt_pknorm_i16(y0, y1);
  return cv.u;
#else
  u32 b0 = (u32)(int)fmaf(c0, 4.0f, 15315.354f);
  u32 b1 = (u32)(int)fmaf(c1, 4.0f, 15315.354f);
  return __builtin_amdgcn_perm(b1, b0, 0x05040100u);
#endif
}

// ================= fused prep =================
// blocks 0..1023   : L2-normalize 16 rows each of [lb;anchor;pos], scale by
//                    16*SQRTC, fp8 e4m3 into swizzled F image; zero P12 slice.
// blocks 1024..1087: build f16 V fragments (32-row pair-groups) + per-block
//                    class-count partials.
__global__ void kprep2(const float* __restrict__ lb, const float* __restrict__ an,
                       const float* __restrict__ po, const float* __restrict__ onehot,
                       const float* __restrict__ l1, const float* __restrict__ l2,
                       u8* __restrict__ F8, f16_t* __restrict__ VF,
                       float* __restrict__ clsPart, float* __restrict__ P12) {
  __shared__ float Vtmp[256 * 16];
  __shared__ float lcnt[NC];
  int b = blockIdx.x;
  int t = threadIdx.x;

  if (b < 1024) {
    if (t < 192) P12[(size_t)b * 192 + t] = 0.0f;  // 1024*192 = NROWS*VW
    int row = b * 16 + (t >> 4);
    int c = t & 15;           // lane's 8 floats = k bytes c*8 .. c*8+7
    const float* src;
    if (row < NLB) src = lb + (size_t)row * DD;
    else if (row < NLB + NULB) src = an + (size_t)(row - NLB) * DD;
    else src = po + (size_t)(row - NLB - NULB) * DD;
    float4 v0 = ((const float4*)src)[c * 2];
    float4 v1 = ((const float4*)src)[c * 2 + 1];
    float ss = v0.x*v0.x + v0.y*v0.y + v0.z*v0.z + v0.w*v0.w
             + v1.x*v1.x + v1.y*v1.y + v1.z*v1.z + v1.w*v1.w;
#pragma unroll
    for (int off = 8; off >= 1; off >>= 1) ss += __shfl_xor(ss, off);
    float inv = (16.0f * SQRTC) / fmaxf(sqrtf(ss), 1e-12f);
    u32 d0 = (u32)__builtin_amdgcn_cvt_pk_fp8_f32(v0.x*inv, v0.y*inv, 0, false);
    d0 = (u32)__builtin_amdgcn_cvt_pk_fp8_f32(v0.z*inv, v0.w*inv, d0, true);
    u32 d1 = (u32)__builtin_amdgcn_cvt_pk_fp8_f32(v1.x*inv, v1.y*inv, 0, false);
    d1 = (u32)__builtin_amdgcn_cvt_pk_fp8_f32(v1.z*inv, v1.w*inv, d1, true);
    uint2 dd = {d0, d1};
    *(uint2*)(F8 + f8idx(row, c >> 1) + ((c & 1) << 3)) = dd;
    return;
  }

  // ---- V build: 256 rows/block over all 16384 output rows ----
  if (t < NC) lcnt[t] = 0.0f;
  __syncthreads();
  int gid = (b - 1024) * 256 + t;
  float p[16];
  p[10] = 1.0f; p[11] = 0.f; p[12] = 0.f; p[13] = 0.f; p[14] = 0.f; p[15] = 0.f;
  if (gid < NLB) {
    int idx = 0;
#pragma unroll
    for (int c = 0; c < NC; ++c) {
      p[c] = onehot[(size_t)gid * NC + c];
      if (p[c] == 1.0f) idx = c;
    }
    atomicAdd(&lcnt[idx], 1.0f);
  } else {
    int r = (gid < NLB + NULB) ? (gid - NLB) : (gid - NLB - NULB);
    bool count = (gid < NLB + NULB);
    float a[NC], bb[NC];
#pragma unroll
    for (int c = 0; c < NC; ++c) { a[c] = l1[(size_t)r * NC + c]; bb[c] = l2[(size_t)r * NC + c]; }
    float m1 = a[0], m2 = bb[0];
#pragma unroll
    for (int c = 1; c < NC; ++c) { m1 = fmaxf(m1, a[c]); m2 = fmaxf(m2, bb[c]); }
    float s1 = 0.0f, s2 = 0.0f;
#pragma unroll
    for (int c = 0; c < NC; ++c) {
      s1 += expf(2.0f * (a[c] - m1));
      s2 += expf(2.0f * (bb[c] - m2));
    }
    bool take1 = (s1 <= s2);  // max(prob1)=1/s1 >= 1/s2=max(prob2)
    float g[NC];
#pragma unroll
    for (int c = 0; c < NC; ++c) g[c] = take1 ? a[c] : bb[c];
    float mg = g[0];
#pragma unroll
    for (int c = 1; c < NC; ++c) mg = fmaxf(mg, g[c]);
    float e[NC]; float sg = 0.0f;
#pragma unroll
    for (int c = 0; c < NC; ++c) { e[c] = expf(g[c] - mg); sg += e[c]; }
    float msk[NC];
#pragma unroll
    for (int c = 0; c < NC; ++c) msk[c] = ((e[c] / sg) >= 0.95f) ? g[c] : 0.0f;
    float mx = msk[0]; int mi = 0;
#pragma unroll
    for (int c = 1; c < NC; ++c) if (msk[c] > mx) { mx = msk[c]; mi = c; }
    if (count && mx != 0.0f) atomicAdd(&lcnt[mi], 2.0f);
    float mm = 2.0f * msk[0];
#pragma unroll
    for (int c = 1; c < NC; ++c) mm = fmaxf(mm, 2.0f * msk[c]);
    float q[NC]; float sp = 0.0f;
#pragma unroll
    for (int c = 0; c < NC; ++c) { q[c] = expf(2.0f * msk[c] - mm); sp += q[c]; }
#pragma unroll
    for (int c = 0; c < NC; ++c) p[c] = q[c] / sp;
  }
#pragma unroll
  for (int c = 0; c < 16; ++c) Vtmp[t * 16 + c] = p[c];
  __syncthreads();
  if (t < 16) clsPart[(size_t)(b - 1024) * 16 + t] = (t < NC) ? lcnt[t] : 0.0f;
  // scatter to VF f16 pair-frag layout: 512 16B chunks/block, 2 per thread
  int gbase = (b - 1024) * 8;   // 8 pair-groups of 32 rows per 256-row block
#pragma unroll
  for (int u = 0; u < 2; ++u) {
    int cid = u * 256 + t;       // 0..511
    int G = cid >> 6;            // local pair-group 0..7
    int l = cid & 63;
    int q = l >> 4;
    int n = l & 15;
    union { f16_t h[8]; uint4 uu; } pk;
#pragma unroll
    for (int d = 0; d < 4; ++d) {
      pk.h[d]     = (f16_t)Vtmp[(G * 32      + q * 4 + d) * 16 + n];
      pk.h[4 + d] = (f16_t)Vtmp[(G * 32 + 16 + q * 4 + d) * 16 + n];
    }
    *(uint4*)(VF + ((size_t)(gbase + G) * 64 + l) * 8) = pk.uu;
  }
}

// ================= attention partials =================
// BJ=64 double-buffered: LDS = 2*(8K F + 2K V) = 20480 B -> EIGHT blocks/CU
// (163840/20480 = 8), grid (64,32) = 2048 = 8 x 256 CUs exactly, no tail.
// 8 waves/SIMD (vs R13's 4) fills the ~30% idle R13 measured; VGPR 52 <= 64
// budget so no spill (R10 lesson checked).
// QK: mfma_scale_f32_16x16x128_f8f6f4 (one MFMA = all K=128, 2x bf16 rate).
// PV: even/odd 16-row chunks paired in one mfma_f32_16x16x32_f16.
__launch_bounds__(256, 8)
__global__ void kattn(const u8* __restrict__ F8, const f16_t* __restrict__ VF,
                      float* __restrict__ P12) {
  __shared__ u8 Fs[2][BJ * 128];       // 2 x 8 KB fp8 swizzled tile image
  __shared__ uint4 Vs4[2][128];        // 2 x 2 KB f16 V pair-frags
  int t = threadIdx.x;
  int lane = t & 63;
  int wave = t >> 6;    // 0..3
  int q = lane >> 4;    // 0..3
  int r = lane & 15;    // 0..15
  int i0 = blockIdx.x * BI + wave * 64;
  int jbase = blockIdx.y * JSEG;

  // stationary B-frags: 4 i-sets, 32 fp8 bytes/lane (chunks 2q, 2q+1 of row)
  i32x8 bfr[4];
#pragma unroll
  for (int s = 0; s < 4; ++s) {
    int row = i0 + s * 16 + r;
    union { uint4 h[2]; i32x8 v; } bb;
    bb.h[0] = *(const uint4*)(F8 + f8idx(row, 2 * q));
    bb.h[1] = *(const uint4*)(F8 + f8idx(row, 2 * q + 1));
    bfr[s] = bb.v;
  }

  f32x4 acc[4];
#pragma unroll
  for (int s = 0; s < 4; ++s) acc[s] = (f32x4){0.f, 0.f, 0.f, 0.f};
  const f32x4 kZero = {0.f, 0.f, 0.f, 0.f};

  auto stage = [&](int buf, int j0) {
    // F sub-tile: 8 KB contiguous in the global image (j0 multiple of 64)
    const uint4* srcF = (const uint4*)(F8 + ((size_t)(j0 >> 7) << 14)
                                          + ((size_t)(j0 & 127) << 7));
#pragma unroll
    for (int k = 0; k < 2; ++k) {
      int off = ((k * 4 + wave) << 6) + lane;   // 16B-chunk idx 0..511
      __builtin_amdgcn_global_load_lds(
          (const __attribute__((address_space(1))) uint4*)(srcF + off),
          (__attribute__((address_space(3))) uint4*)((uint4*)Fs[buf] + off), 16, 0, 0);
    }
    // V: 2 pair-groups = 128 uint4
    if (t < 128) {
      const uint4* srcV = (const uint4*)VF + ((size_t)(j0 >> 5) << 6);
      __builtin_amdgcn_global_load_lds(
          (const __attribute__((address_space(1))) uint4*)(srcV + t),
          (__attribute__((address_space(3))) uint4*)(Vs4[buf] + t), 16, 0, 0);
    }
  };

  auto compute = [&](int buf) {
    const u8* fsb = Fs[buf];
    const uint4* vsb = Vs4[buf];
#pragma unroll
    for (int jp = 0; jp < BJ / 32; ++jp) {   // pairs of 16-row j-chunks
      union { uint4 h[2]; i32x8 v; } afe, afo;
      const u8* re = fsb + (jp * 32 + r) * 128;       // even chunk row
      const u8* ro = re + 16 * 128;                   // odd chunk row
      int c0 = (((2 * q) ^ (r & 7)) & 7) << 4;
      int c1 = (((2 * q + 1) ^ (r & 7)) & 7) << 4;
      afe.h[0] = *(const uint4*)(re + c0);
      afe.h[1] = *(const uint4*)(re + c1);
      afo.h[0] = *(const uint4*)(ro + c0);
      afo.h[1] = *(const uint4*)(ro + c1);
      union { uint4 qd; f16x8 v; } bv;
      bv.qd = vsb[jp * 64 + lane];
#pragma unroll
      for (int s = 0; s < 4; ++s) {
        f32x4 ce = __builtin_amdgcn_mfma_scale_f32_16x16x128_f8f6f4(
            afe.v, bfr[s], kZero, 0, 0, 0, 0x7F7F7F7Fu, 0, 0x7F7F7F7Fu);
        f32x4 co = __builtin_amdgcn_mfma_scale_f32_16x16x128_f8f6f4(
            afo.v, bfr[s], kZero, 0, 0, 0, 0x7F7F7F7Fu, 0, 0x7F7F7F7Fu);
        union { u32 u[4]; f16x8 v; } pf;
        pf.u[0] = packexp2f16(ce[0], ce[1]);
        pf.u[1] = packexp2f16(ce[2], ce[3]);
        pf.u[2] = packexp2f16(co[0], co[1]);
        pf.u[3] = packexp2f16(co[2], co[3]);
        acc[s] = __builtin_amdgcn_mfma_f32_16x16x32_f16(pf.v, bv.v, acc[s], 0, 0, 0);
      }
    }
  };

  // ---- double-buffered pipeline over the 8 tiles of this j-segment ----
  stage(0, jbase);
  __syncthreads();
#pragma unroll
  for (int jt = 0; jt < JSEG / BJ - 1; ++jt) {
    stage((jt + 1) & 1, jbase + (jt + 1) * BJ);  // prefetch overlaps compute
    compute(jt & 1);
    __syncthreads();  // drain waits on loads that ran under compute
  }
  compute((JSEG / BJ - 1) & 1);

  // acc[s] lane(q,r) reg rg = partial[row = i0+s*16+q*4+rg][col = r]
  if (r < 11) {
#pragma unroll
    for (int s = 0; s < 4; ++s) {
      float* op = P12 + (size_t)(i0 + s * 16 + q * 4) * VW + r;
      atomicAdd(&op[0 * VW], acc[s][0]);
      atomicAdd(&op[1 * VW], acc[s][1]);
      atomicAdd(&op[2 * VW], acc[s][2]);
      atomicAdd(&op[3 * VW], acc[s][3]);
    }
  }
}

// ---------------- finalize: class-count reduce + divides ----------------
__global__ void kfinal(float* __restrict__ out, const float* __restrict__ P12,
                       const float* __restrict__ clsPart) {
  __shared__ float clsS[16];
  int t = threadIdx.x;
  if (t < 64) {
    const float4* cp = (const float4*)clsPart;  // 64 rows x 4 float4
    float4 c0 = cp[t * 4], c1 = cp[t * 4 + 1], c2 = cp[t * 4 + 2], c3 = cp[t * 4 + 3];
#pragma unroll
    for (int off = 32; off >= 1; off >>= 1) {
      c0.x += __shfl_xor(c0.x, off); c0.y += __shfl_xor(c0.y, off);
      c0.z += __shfl_xor(c0.z, off); c0.w += __shfl_xor(c0.w, off);
      c1.x += __shfl_xor(c1.x, off); c1.y += __shfl_xor(c1.y, off);
      c1.z += __shfl_xor(c1.z, off); c1.w += __shfl_xor(c1.w, off);
      c2.x += __shfl_xor(c2.x, off); c2.y += __shfl_xor(c2.y, off);
    }
    if (t == 0) {
      *(float4*)&clsS[0] = c0;
      *(float4*)&clsS[4] = c1;
      clsS[8] = c2.x; clsS[9] = c2.y;
      clsS[10] = 0.f; clsS[11] = 0.f; clsS[12] = 0.f;
      clsS[13] = 0.f; clsS[14] = 0.f; clsS[15] = 0.f;
    }
  }
  __syncthreads();
  float d[NC]; float tot = 0.0f;
#pragma unroll
  for (int c = 0; c < NC; ++c) { d[c] = clsS[c]; tot += d[c]; }
  int row = blockIdx.x * 256 + t;  // 64 blocks x 256
  const float* pr = P12 + (size_t)row * VW;
  float rs = 1.0f / pr[10];
  float* op = out + (size_t)row * NC;
#pragma unroll
  for (int c = 0; c < NC; ++c) {
    float den = (d[c] == 0.0f) ? tot : d[c];
    op[c] = pr[c] * rs / den;
  }
}

extern "C" void kernel_launch(void* const* d_in, const int* in_sizes, int n_in,
                              void* d_out, int out_size, void* d_ws, size_t ws_size,
                              hipStream_t stream) {
  const float* anchor   = (const float*)d_in[0];  // 6144x128
  const float* positive = (const float*)d_in[1];  // 6144x128
  const float* lbfeat   = (const float*)d_in[2];  // 4096x128
  const float* onehot   = (const float*)d_in[3];  // 4096x10
  const float* l1       = (const float*)d_in[4];  // 6144x10
  const float* l2       = (const float*)d_in[5];  // 6144x10
  float* out = (float*)d_out;                     // 16384x10

  char* ws = (char*)d_ws;
  u8*     F8      = (u8*)ws;                                   // 2 MiB fp8 swizzled image
  f16_t*  VF      = (f16_t*)(ws + 2097152);                    // 512 KiB f16 pair-frags
  float*  P12     = (float*)(ws + 2097152 + 524288);           // 768 KiB
  float*  clsPart = (float*)(ws + 2097152 + 524288 + 786432);  // 4 KiB

  kprep2<<<1088, 256, 0, stream>>>(lbfeat, anchor, positive, onehot, l1, l2,
                                   F8, VF, clsPart, P12);
  kattn<<<dim3(NROWS / BI, SEG), 256, 0, stream>>>(F8, VF, P12);
  kfinal<<<NROWS / 256, 256, 0, stream>>>(out, P12, clsPart);
}

// Round 15
// 123.578 us; speedup vs baseline: 2.4929x; 2.4929x over previous
//
#include <hip/hip_runtime.h>
#include <hip/hip_bf16.h>

#define NLB 4096
#define NULB 6144
#define NROWS 16384   // 4096 + 2*6144
#define DD 128
#define NC 10
#define VW 12                // P12 row width: 10 numerators + denom + pad
#define SEG 32
#define JSEG (NROWS / SEG)   // 512
#define BI 256               // i-rows per block (4 waves x 64)
#define BJ 64                // j-rows per LDS tile (double-buffered)
#define SQRTC 1.6986437f     // sqrt(2*log2(e))
// F stored as fp8 of (16*SQRTC*f)  ->  QK result cfr = 256 * C * dot
#define FE_BIAS  1.06498747e9f   // f32 fallback bias

typedef __bf16 bf16_t;
typedef _Float16 f16_t;
typedef f16_t f16x8 __attribute__((ext_vector_type(8)));
typedef float f32x4 __attribute__((ext_vector_type(4)));
typedef short i16x2 __attribute__((ext_vector_type(2)));
typedef int i32x8 __attribute__((ext_vector_type(8)));
typedef unsigned int u32;
typedef unsigned char u8;

// fp8 F global layout = swizzled LDS image, 128-row tiles of 128-byte rows:
//   byte address(row, 16B-chunk c0..7) =
//     (row>>7)*16384 + (row&127)*128 + ((c ^ (row&7)) << 4)
// 64-row aligned sub-tiles are contiguous 8 KB spans -> BJ=64 staging works.
__device__ __forceinline__ size_t f8idx(int row, int c) {
  return ((size_t)(row >> 7) << 14) + (size_t)((row & 127) << 7)
       + (size_t)(((c ^ (row & 7)) & 7) << 4);
}

// pack two f16(2^(c/256)) into one dword (fma + pknorm per pair).
// f16 bits of 2^x ~= round(1024x + 15315.35); x = c/256 -> 4*c.
// pknorm: i16 = round(y*32767) -> y = c*(4/32767) + 15315.35/32767.
// staircase rel err ~0.2%, mean-zero, common-mode num/denom.
__device__ __forceinline__ u32 packexp2f16(float c0, float c1) {
#if __has_builtin(__builtin_amdgcn_cvt_pknorm_i16)
  float y0 = fmaf(c0, 1.2207465e-4f, 0.46740490f);
  float y1 = fmaf(c1, 1.2207465e-4f, 0.46740490f);
  union { i16x2 p; u32 u; } cv;
  cv.p = __builtin_amdgcn_cvt_pknorm_i16(y0, y1);
  return cv.u;
#else
  u32 b0 = (u32)(int)fmaf(c0, 4.0f, 15315.354f);
  u32 b1 = (u32)(int)fmaf(c1, 4.0f, 15315.354f);
  return __builtin_amdgcn_perm(b1, b0, 0x05040100u);
#endif
}

// ================= fused prep =================
// blocks 0..1023   : L2-normalize 16 rows each of [lb;anchor;pos], scale by
//                    16*SQRTC, fp8 e4m3 into swizzled F image; zero P12 slice.
// blocks 1024..1087: build f16 V fragments (32-row pair-groups) + per-block
//                    class-count partials.
__global__ void kprep2(const float* __restrict__ lb, const float* __restrict__ an,
                       const float* __restrict__ po, const float* __restrict__ onehot,
                       const float* __restrict__ l1, const float* __restrict__ l2,
                       u8* __restrict__ F8, f16_t* __restrict__ VF,
                       float* __restrict__ clsPart, float* __restrict__ P12) {
  __shared__ float Vtmp[256 * 16];
  __shared__ float lcnt[NC];
  int b = blockIdx.x;
  int t = threadIdx.x;

  if (b < 1024) {
    if (t < 192) P12[(size_t)b * 192 + t] = 0.0f;  // 1024*192 = NROWS*VW
    int row = b * 16 + (t >> 4);
    int c = t & 15;           // lane's 8 floats = k bytes c*8 .. c*8+7
    const float* src;
    if (row < NLB) src = lb + (size_t)row * DD;
    else if (row < NLB + NULB) src = an + (size_t)(row - NLB) * DD;
    else src = po + (size_t)(row - NLB - NULB) * DD;
    float4 v0 = ((const float4*)src)[c * 2];
    float4 v1 = ((const float4*)src)[c * 2 + 1];
    float ss = v0.x*v0.x + v0.y*v0.y + v0.z*v0.z + v0.w*v0.w
             + v1.x*v1.x + v1.y*v1.y + v1.z*v1.z + v1.w*v1.w;
#pragma unroll
    for (int off = 8; off >= 1; off >>= 1) ss += __shfl_xor(ss, off);
    float inv = (16.0f * SQRTC) / fmaxf(sqrtf(ss), 1e-12f);
    u32 d0 = (u32)__builtin_amdgcn_cvt_pk_fp8_f32(v0.x*inv, v0.y*inv, 0, false);
    d0 = (u32)__builtin_amdgcn_cvt_pk_fp8_f32(v0.z*inv, v0.w*inv, d0, true);
    u32 d1 = (u32)__builtin_amdgcn_cvt_pk_fp8_f32(v1.x*inv, v1.y*inv, 0, false);
    d1 = (u32)__builtin_amdgcn_cvt_pk_fp8_f32(v1.z*inv, v1.w*inv, d1, true);
    uint2 dd = {d0, d1};
    *(uint2*)(F8 + f8idx(row, c >> 1) + ((c & 1) << 3)) = dd;
    return;
  }

  // ---- V build: 256 rows/block over all 16384 output rows ----
  if (t < NC) lcnt[t] = 0.0f;
  __syncthreads();
  int gid = (b - 1024) * 256 + t;
  float p[16];
  p[10] = 1.0f; p[11] = 0.f; p[12] = 0.f; p[13] = 0.f; p[14] = 0.f; p[15] = 0.f;
  if (gid < NLB) {
    int idx = 0;
#pragma unroll
    for (int c = 0; c < NC; ++c) {
      p[c] = onehot[(size_t)gid * NC + c];
      if (p[c] == 1.0f) idx = c;
    }
    atomicAdd(&lcnt[idx], 1.0f);
  } else {
    int r = (gid < NLB + NULB) ? (gid - NLB) : (gid - NLB - NULB);
    bool count = (gid < NLB + NULB);
    float a[NC], bb[NC];
#pragma unroll
    for (int c = 0; c < NC; ++c) { a[c] = l1[(size_t)r * NC + c]; bb[c] = l2[(size_t)r * NC + c]; }
    float m1 = a[0], m2 = bb[0];
#pragma unroll
    for (int c = 1; c < NC; ++c) { m1 = fmaxf(m1, a[c]); m2 = fmaxf(m2, bb[c]); }
    float s1 = 0.0f, s2 = 0.0f;
#pragma unroll
    for (int c = 0; c < NC; ++c) {
      s1 += expf(2.0f * (a[c] - m1));
      s2 += expf(2.0f * (bb[c] - m2));
    }
    bool take1 = (s1 <= s2);  // max(prob1)=1/s1 >= 1/s2=max(prob2)
    float g[NC];
#pragma unroll
    for (int c = 0; c < NC; ++c) g[c] = take1 ? a[c] : bb[c];
    float mg = g[0];
#pragma unroll
    for (int c = 1; c < NC; ++c) mg = fmaxf(mg, g[c]);
    float e[NC]; float sg = 0.0f;
#pragma unroll
    for (int c = 0; c < NC; ++c) { e[c] = expf(g[c] - mg); sg += e[c]; }
    float msk[NC];
#pragma unroll
    for (int c = 0; c < NC; ++c) msk[c] = ((e[c] / sg) >= 0.95f) ? g[c] : 0.0f;
    float mx = msk[0]; int mi = 0;
#pragma unroll
    for (int c = 1; c < NC; ++c) if (msk[c] > mx) { mx = msk[c]; mi = c; }
    if (count && mx != 0.0f) atomicAdd(&lcnt[mi], 2.0f);
    float mm = 2.0f * msk[0];
#pragma unroll
    for (int c = 1; c < NC; ++c) mm = fmaxf(mm, 2.0f * msk[c]);
    float q[NC]; float sp = 0.0f;
#pragma unroll
    for (int c = 0; c < NC; ++c) { q[c] = expf(2.0f * msk[c] - mm); sp += q[c]; }
#pragma unroll
    for (int c = 0; c < NC; ++c) p[c] = q[c] / sp;
  }
#pragma unroll
  for (int c = 0; c < 16; ++c) Vtmp[t * 16 + c] = p[c];
  __syncthreads();
  if (t < 16) clsPart[(size_t)(b - 1024) * 16 + t] = (t < NC) ? lcnt[t] : 0.0f;
  // scatter to VF f16 pair-frag layout: 512 16B chunks/block, 2 per thread
  int gbase = (b - 1024) * 8;   // 8 pair-groups of 32 rows per 256-row block
#pragma unroll
  for (int u = 0; u < 2; ++u) {
    int cid = u * 256 + t;       // 0..511
    int G = cid >> 6;            // local pair-group 0..7
    int l = cid & 63;
    int q = l >> 4;
    int n = l & 15;
    union { f16_t h[8]; uint4 uu; } pk;
#pragma unroll
    for (int d = 0; d < 4; ++d) {
      pk.h[d]     = (f16_t)Vtmp[(G * 32      + q * 4 + d) * 16 + n];
      pk.h[4 + d] = (f16_t)Vtmp[(G * 32 + 16 + q * 4 + d) * 16 + n];
    }
    *(uint4*)(VF + ((size_t)(gbase + G) * 64 + l) * 8) = pk.uu;
  }
}

// ================= attention partials =================
// BJ=64 double-buffered: LDS = 2*(8K F + 2K V) = 20480 B -> 8 blocks/CU by
// LDS. __launch_bounds__(256,4): R14's (256,8) FORCED the allocator to a
// 64-reg budget and spilled (VGPR_Count 32, ~950 MB scratch traffic); the
// natural allocation is ~52 regs (R13), which already supports 8 waves/SIMD
// -- occupancy is set by LDS, not by the bounds arg. Grid (64,32) = 2048 =
// 8 x 256 CUs exactly, no tail.
// QK: mfma_scale_f32_16x16x128_f8f6f4 (one MFMA = all K=128, 2x bf16 rate).
// PV: even/odd 16-row chunks paired in one mfma_f32_16x16x32_f16.
__launch_bounds__(256, 4)
__global__ void kattn(const u8* __restrict__ F8, const f16_t* __restrict__ VF,
                      float* __restrict__ P12) {
  __shared__ u8 Fs[2][BJ * 128];       // 2 x 8 KB fp8 swizzled tile image
  __shared__ uint4 Vs4[2][128];        // 2 x 2 KB f16 V pair-frags
  int t = threadIdx.x;
  int lane = t & 63;
  int wave = t >> 6;    // 0..3
  int q = lane >> 4;    // 0..3
  int r = lane & 15;    // 0..15
  int i0 = blockIdx.x * BI + wave * 64;
  int jbase = blockIdx.y * JSEG;

  // stationary B-frags: 4 i-sets, 32 fp8 bytes/lane (chunks 2q, 2q+1 of row)
  i32x8 bfr[4];
#pragma unroll
  for (int s = 0; s < 4; ++s) {
    int row = i0 + s * 16 + r;
    union { uint4 h[2]; i32x8 v; } bb;
    bb.h[0] = *(const uint4*)(F8 + f8idx(row, 2 * q));
    bb.h[1] = *(const uint4*)(F8 + f8idx(row, 2 * q + 1));
    bfr[s] = bb.v;
  }

  f32x4 acc[4];
#pragma unroll
  for (int s = 0; s < 4; ++s) acc[s] = (f32x4){0.f, 0.f, 0.f, 0.f};
  const f32x4 kZero = {0.f, 0.f, 0.f, 0.f};

  auto stage = [&](int buf, int j0) {
    // F sub-tile: 8 KB contiguous in the global image (j0 multiple of 64)
    const uint4* srcF = (const uint4*)(F8 + ((size_t)(j0 >> 7) << 14)
                                          + ((size_t)(j0 & 127) << 7));
#pragma unroll
    for (int k = 0; k < 2; ++k) {
      int off = ((k * 4 + wave) << 6) + lane;   // 16B-chunk idx 0..511
      __builtin_amdgcn_global_load_lds(
          (const __attribute__((address_space(1))) uint4*)(srcF + off),
          (__attribute__((address_space(3))) uint4*)((uint4*)Fs[buf] + off), 16, 0, 0);
    }
    // V: 2 pair-groups = 128 uint4
    if (t < 128) {
      const uint4* srcV = (const uint4*)VF + ((size_t)(j0 >> 5) << 6);
      __builtin_amdgcn_global_load_lds(
          (const __attribute__((address_space(1))) uint4*)(srcV + t),
          (__attribute__((address_space(3))) uint4*)(Vs4[buf] + t), 16, 0, 0);
    }
  };

  auto compute = [&](int buf) {
    const u8* fsb = Fs[buf];
    const uint4* vsb = Vs4[buf];
#pragma unroll
    for (int jp = 0; jp < BJ / 32; ++jp) {   // pairs of 16-row j-chunks
      union { uint4 h[2]; i32x8 v; } afe, afo;
      const u8* re = fsb + (jp * 32 + r) * 128;       // even chunk row
      const u8* ro = re + 16 * 128;                   // odd chunk row
      int c0 = (((2 * q) ^ (r & 7)) & 7) << 4;
      int c1 = (((2 * q + 1) ^ (r & 7)) & 7) << 4;
      afe.h[0] = *(const uint4*)(re + c0);
      afe.h[1] = *(const uint4*)(re + c1);
      afo.h[0] = *(const uint4*)(ro + c0);
      afo.h[1] = *(const uint4*)(ro + c1);
      union { uint4 qd; f16x8 v; } bv;
      bv.qd = vsb[jp * 64 + lane];
#pragma unroll
      for (int s = 0; s < 4; ++s) {
        f32x4 ce = __builtin_amdgcn_mfma_scale_f32_16x16x128_f8f6f4(
            afe.v, bfr[s], kZero, 0, 0, 0, 0x7F7F7F7Fu, 0, 0x7F7F7F7Fu);
        f32x4 co = __builtin_amdgcn_mfma_scale_f32_16x16x128_f8f6f4(
            afo.v, bfr[s], kZero, 0, 0, 0, 0x7F7F7F7Fu, 0, 0x7F7F7F7Fu);
        union { u32 u[4]; f16x8 v; } pf;
        pf.u[0] = packexp2f16(ce[0], ce[1]);
        pf.u[1] = packexp2f16(ce[2], ce[3]);
        pf.u[2] = packexp2f16(co[0], co[1]);
        pf.u[3] = packexp2f16(co[2], co[3]);
        acc[s] = __builtin_amdgcn_mfma_f32_16x16x32_f16(pf.v, bv.v, acc[s], 0, 0, 0);
      }
    }
  };

  // ---- double-buffered pipeline over the 8 tiles of this j-segment ----
  stage(0, jbase);
  __syncthreads();
#pragma unroll
  for (int jt = 0; jt < JSEG / BJ - 1; ++jt) {
    stage((jt + 1) & 1, jbase + (jt + 1) * BJ);  // prefetch overlaps compute
    compute(jt & 1);
    __syncthreads();  // drain waits on loads that ran under compute
  }
  compute((JSEG / BJ - 1) & 1);

  // acc[s] lane(q,r) reg rg = partial[row = i0+s*16+q*4+rg][col = r]
  if (r < 11) {
#pragma unroll
    for (int s = 0; s < 4; ++s) {
      float* op = P12 + (size_t)(i0 + s * 16 + q * 4) * VW + r;
      atomicAdd(&op[0 * VW], acc[s][0]);
      atomicAdd(&op[1 * VW], acc[s][1]);
      atomicAdd(&op[2 * VW], acc[s][2]);
      atomicAdd(&op[3 * VW], acc[s][3]);
    }
  }
}

// ---------------- finalize: class-count reduce + divides ----------------
__global__ void kfinal(float* __restrict__ out, const float* __restrict__ P12,
                       const float* __restrict__ clsPart) {
  __shared__ float clsS[16];
  int t = threadIdx.x;
  if (t < 64) {
    const float4* cp = (const float4*)clsPart;  // 64 rows x 4 float4
    float4 c0 = cp[t * 4], c1 = cp[t * 4 + 1], c2 = cp[t * 4 + 2], c3 = cp[t * 4 + 3];
#pragma unroll
    for (int off = 32; off >= 1; off >>= 1) {
      c0.x += __shfl_xor(c0.x, off); c0.y += __shfl_xor(c0.y, off);
      c0.z += __shfl_xor(c0.z, off); c0.w += __shfl_xor(c0.w, off);
      c1.x += __shfl_xor(c1.x, off); c1.y += __shfl_xor(c1.y, off);
      c1.z += __shfl_xor(c1.z, off); c1.w += __shfl_xor(c1.w, off);
      c2.x += __shfl_xor(c2.x, off); c2.y += __shfl_xor(c2.y, off);
    }
    if (t == 0) {
      *(float4*)&clsS[0] = c0;
      *(float4*)&clsS[4] = c1;
      clsS[8] = c2.x; clsS[9] = c2.y;
      clsS[10] = 0.f; clsS[11] = 0.f; clsS[12] = 0.f;
      clsS[13] = 0.f; clsS[14] = 0.f; clsS[15] = 0.f;
    }
  }
  __syncthreads();
  float d[NC]; float tot = 0.0f;
#pragma unroll
  for (int c = 0; c < NC; ++c) { d[c] = clsS[c]; tot += d[c]; }
  int row = blockIdx.x * 256 + t;  // 64 blocks x 256
  const float* pr = P12 + (size_t)row * VW;
  float rs = 1.0f / pr[10];
  float* op = out + (size_t)row * NC;
#pragma unroll
  for (int c = 0; c < NC; ++c) {
    float den = (d[c] == 0.0f) ? tot : d[c];
    op[c] = pr[c] * rs / den;
  }
}

extern "C" void kernel_launch(void* const* d_in, const int* in_sizes, int n_in,
                              void* d_out, int out_size, void* d_ws, size_t ws_size,
                              hipStream_t stream) {
  const float* anchor   = (const float*)d_in[0];  // 6144x128
  const float* positive = (const float*)d_in[1];  // 6144x128
  const float* lbfeat   = (const float*)d_in[2];  // 4096x128
  const float* onehot   = (const float*)d_in[3];  // 4096x10
  const float* l1       = (const float*)d_in[4];  // 6144x10
  const float* l2       = (const float*)d_in[5];  // 6144x10
  float* out = (float*)d_out;                     // 16384x10

  char* ws = (char*)d_ws;
  u8*     F8      = (u8*)ws;                                   // 2 MiB fp8 swizzled image
  f16_t*  VF      = (f16_t*)(ws + 2097152);                    // 512 KiB f16 pair-frags
  float*  P12     = (float*)(ws + 2097152 + 524288);           // 768 KiB
  float*  clsPart = (float*)(ws + 2097152 + 524288 + 786432);  // 4 KiB

  kprep2<<<1088, 256, 0, stream>>>(lbfeat, anchor, positive, onehot, l1, l2,
                                   F8, VF, clsPart, P12);
  kattn<<<dim3(NROWS / BI, SEG), 256, 0, stream>>>(F8, VF, P12);
  kfinal<<<NROWS / 256, 256, 0, stream>>>(out, P12, clsPart);
}

// Round 16
// 114.804 us; speedup vs baseline: 2.6835x; 1.0764x over previous
//
#include <hip/hip_runtime.h>
#include <hip/hip_bf16.h>

#define NLB 4096
#define NULB 6144
#define NROWS 16384   // 4096 + 2*6144
#define DD 128
#define NC 10
#define VW 12                // P12 row width: 10 numerators + denom + pad
#define SEG 16
#define JSEG (NROWS / SEG)   // 1024
#define BI 256               // i-rows per block (4 waves x 64)
#define BJ 128               // j-rows per LDS tile (double-buffered)
#define SQRTC 1.6986437f     // sqrt(2*log2(e))
// F stored as fp8 of (16*SQRTC*f)  ->  QK result cfr = 256 * C * dot
#define FE_BIAS  1.06498747e9f   // f32 fallback bias

typedef __bf16 bf16_t;
typedef _Float16 f16_t;
typedef f16_t f16x8 __attribute__((ext_vector_type(8)));
typedef float f32x4 __attribute__((ext_vector_type(4)));
typedef short i16x2 __attribute__((ext_vector_type(2)));
typedef int i32x8 __attribute__((ext_vector_type(8)));
typedef unsigned int u32;
typedef unsigned char u8;

// fp8 F global layout = swizzled LDS image, 128-row tiles of 128-byte rows:
//   byte address(row, 16B-chunk c0..7) =
//     (row>>7)*16384 + (row&127)*128 + ((c ^ (row&7)) << 4)
__device__ __forceinline__ size_t f8idx(int row, int c) {
  return ((size_t)(row >> 7) << 14) + (size_t)((row & 127) << 7)
       + (size_t)(((c ^ (row & 7)) & 7) << 4);
}

// pack two f16(2^(c/256)) into one dword (fma + pknorm per pair).
// f16 bits of 2^x ~= round(1024x + 15315.35); x = c/256 -> 4*c.
// pknorm: i16 = round(y*32767) -> y = c*(4/32767) + 15315.35/32767.
// staircase rel err ~0.2%, mean-zero, common-mode num/denom.
__device__ __forceinline__ u32 packexp2f16(float c0, float c1) {
#if __has_builtin(__builtin_amdgcn_cvt_pknorm_i16)
  float y0 = fmaf(c0, 1.2207465e-4f, 0.46740490f);
  float y1 = fmaf(c1, 1.2207465e-4f, 0.46740490f);
  union { i16x2 p; u32 u; } cv;
  cv.p = __builtin_amdgcn_cvt_pknorm_i16(y0, y1);
  return cv.u;
#else
  u32 b0 = (u32)(int)fmaf(c0, 4.0f, 15315.354f);
  u32 b1 = (u32)(int)fmaf(c1, 4.0f, 15315.354f);
  return __builtin_amdgcn_perm(b1, b0, 0x05040100u);
#endif
}

// ================= fused prep =================
// blocks 0..1023   : L2-normalize 16 rows each of [lb;anchor;pos], scale by
//                    16*SQRTC, fp8 e4m3 into swizzled F image; zero P12 slice.
// blocks 1024..1087: build f16 V fragments (32-row pair-groups) + per-block
//                    class-count partials.
__global__ void kprep2(const float* __restrict__ lb, const float* __restrict__ an,
                       const float* __restrict__ po, const float* __restrict__ onehot,
                       const float* __restrict__ l1, const float* __restrict__ l2,
                       u8* __restrict__ F8, f16_t* __restrict__ VF,
                       float* __restrict__ clsPart, float* __restrict__ P12) {
  __shared__ float Vtmp[256 * 16];
  __shared__ float lcnt[NC];
  int b = blockIdx.x;
  int t = threadIdx.x;

  if (b < 1024) {
    if (t < 192) P12[(size_t)b * 192 + t] = 0.0f;  // 1024*192 = NROWS*VW
    int row = b * 16 + (t >> 4);
    int c = t & 15;           // lane's 8 floats = k bytes c*8 .. c*8+7
    const float* src;
    if (row < NLB) src = lb + (size_t)row * DD;
    else if (row < NLB + NULB) src = an + (size_t)(row - NLB) * DD;
    else src = po + (size_t)(row - NLB - NULB) * DD;
    float4 v0 = ((const float4*)src)[c * 2];
    float4 v1 = ((const float4*)src)[c * 2 + 1];
    float ss = v0.x*v0.x + v0.y*v0.y + v0.z*v0.z + v0.w*v0.w
             + v1.x*v1.x + v1.y*v1.y + v1.z*v1.z + v1.w*v1.w;
#pragma unroll
    for (int off = 8; off >= 1; off >>= 1) ss += __shfl_xor(ss, off);
    float inv = (16.0f * SQRTC) / fmaxf(sqrtf(ss), 1e-12f);
    u32 d0 = (u32)__builtin_amdgcn_cvt_pk_fp8_f32(v0.x*inv, v0.y*inv, 0, false);
    d0 = (u32)__builtin_amdgcn_cvt_pk_fp8_f32(v0.z*inv, v0.w*inv, d0, true);
    u32 d1 = (u32)__builtin_amdgcn_cvt_pk_fp8_f32(v1.x*inv, v1.y*inv, 0, false);
    d1 = (u32)__builtin_amdgcn_cvt_pk_fp8_f32(v1.z*inv, v1.w*inv, d1, true);
    uint2 dd = {d0, d1};
    *(uint2*)(F8 + f8idx(row, c >> 1) + ((c & 1) << 3)) = dd;
    return;
  }

  // ---- V build: 256 rows/block over all 16384 output rows ----
  if (t < NC) lcnt[t] = 0.0f;
  __syncthreads();
  int gid = (b - 1024) * 256 + t;
  float p[16];
  p[10] = 1.0f; p[11] = 0.f; p[12] = 0.f; p[13] = 0.f; p[14] = 0.f; p[15] = 0.f;
  if (gid < NLB) {
    int idx = 0;
#pragma unroll
    for (int c = 0; c < NC; ++c) {
      p[c] = onehot[(size_t)gid * NC + c];
      if (p[c] == 1.0f) idx = c;
    }
    atomicAdd(&lcnt[idx], 1.0f);
  } else {
    int r = (gid < NLB + NULB) ? (gid - NLB) : (gid - NLB - NULB);
    bool count = (gid < NLB + NULB);
    float a[NC], bb[NC];
#pragma unroll
    for (int c = 0; c < NC; ++c) { a[c] = l1[(size_t)r * NC + c]; bb[c] = l2[(size_t)r * NC + c]; }
    float m1 = a[0], m2 = bb[0];
#pragma unroll
    for (int c = 1; c < NC; ++c) { m1 = fmaxf(m1, a[c]); m2 = fmaxf(m2, bb[c]); }
    float s1 = 0.0f, s2 = 0.0f;
#pragma unroll
    for (int c = 0; c < NC; ++c) {
      s1 += expf(2.0f * (a[c] - m1));
      s2 += expf(2.0f * (bb[c] - m2));
    }
    bool take1 = (s1 <= s2);  // max(prob1)=1/s1 >= 1/s2=max(prob2)
    float g[NC];
#pragma unroll
    for (int c = 0; c < NC; ++c) g[c] = take1 ? a[c] : bb[c];
    float mg = g[0];
#pragma unroll
    for (int c = 1; c < NC; ++c) mg = fmaxf(mg, g[c]);
    float e[NC]; float sg = 0.0f;
#pragma unroll
    for (int c = 0; c < NC; ++c) { e[c] = expf(g[c] - mg); sg += e[c]; }
    float msk[NC];
#pragma unroll
    for (int c = 0; c < NC; ++c) msk[c] = ((e[c] / sg) >= 0.95f) ? g[c] : 0.0f;
    float mx = msk[0]; int mi = 0;
#pragma unroll
    for (int c = 1; c < NC; ++c) if (msk[c] > mx) { mx = msk[c]; mi = c; }
    if (count && mx != 0.0f) atomicAdd(&lcnt[mi], 2.0f);
    float mm = 2.0f * msk[0];
#pragma unroll
    for (int c = 1; c < NC; ++c) mm = fmaxf(mm, 2.0f * msk[c]);
    float q[NC]; float sp = 0.0f;
#pragma unroll
    for (int c = 0; c < NC; ++c) { q[c] = expf(2.0f * msk[c] - mm); sp += q[c]; }
#pragma unroll
    for (int c = 0; c < NC; ++c) p[c] = q[c] / sp;
  }
#pragma unroll
  for (int c = 0; c < 16; ++c) Vtmp[t * 16 + c] = p[c];
  __syncthreads();
  if (t < 16) clsPart[(size_t)(b - 1024) * 16 + t] = (t < NC) ? lcnt[t] : 0.0f;
  // scatter to VF f16 pair-frag layout: 512 16B chunks/block, 2 per thread
  int gbase = (b - 1024) * 8;   // 8 pair-groups of 32 rows per 256-row block
#pragma unroll
  for (int u = 0; u < 2; ++u) {
    int cid = u * 256 + t;       // 0..511
    int G = cid >> 6;            // local pair-group 0..7
    int l = cid & 63;
    int q = l >> 4;
    int n = l & 15;
    union { f16_t h[8]; uint4 uu; } pk;
#pragma unroll
    for (int d = 0; d < 4; ++d) {
      pk.h[d]     = (f16_t)Vtmp[(G * 32      + q * 4 + d) * 16 + n];
      pk.h[4 + d] = (f16_t)Vtmp[(G * 32 + 16 + q * 4 + d) * 16 + n];
    }
    *(uint4*)(VF + ((size_t)(gbase + G) * 64 + l) * 8) = pk.uu;
  }
}

// ================= attention partials =================
// R13 geometry restored (empirical optimum of the occupancy/overhead trade:
// R14 (256,8) spilled; R15 BJ=64/SEG=32 doubled per-block overhead for no
// occupancy gain). BJ=128 double-buffered, LDS = 2*(16K F + 4K V) = 40960
// -> 4 blocks/CU, grid (64,16) = 1024 = 4 x 256 CUs exact, no tail.
// ONE change vs R13: compute() is two-phase per jp -- all 8 QK MFMAs first
// (ce[4]/co[4]), then packs+PVs -- lengthening the MFMA issue run per wave.
// +32 VGPRs live (~80 total), safely under the (256,4) 128-reg budget.
// QK: mfma_scale_f32_16x16x128_f8f6f4 (one MFMA = all K=128, 2x bf16 rate).
// PV: even/odd 16-row chunks paired in one mfma_f32_16x16x32_f16.
__launch_bounds__(256, 4)
__global__ void kattn(const u8* __restrict__ F8, const f16_t* __restrict__ VF,
                      float* __restrict__ P12) {
  __shared__ u8 Fs[2][BJ * 128];       // 2 x 16 KB fp8 swizzled tile image
  __shared__ uint4 Vs4[2][256];        // 2 x 4 KB f16 V pair-frags
  int t = threadIdx.x;
  int lane = t & 63;
  int wave = t >> 6;    // 0..3
  int q = lane >> 4;    // 0..3
  int r = lane & 15;    // 0..15
  int i0 = blockIdx.x * BI + wave * 64;
  int jbase = blockIdx.y * JSEG;

  // stationary B-frags: 4 i-sets, 32 fp8 bytes/lane (chunks 2q, 2q+1 of row)
  i32x8 bfr[4];
#pragma unroll
  for (int s = 0; s < 4; ++s) {
    int row = i0 + s * 16 + r;
    union { uint4 h[2]; i32x8 v; } bb;
    bb.h[0] = *(const uint4*)(F8 + f8idx(row, 2 * q));
    bb.h[1] = *(const uint4*)(F8 + f8idx(row, 2 * q + 1));
    bfr[s] = bb.v;
  }

  f32x4 acc[4];
#pragma unroll
  for (int s = 0; s < 4; ++s) acc[s] = (f32x4){0.f, 0.f, 0.f, 0.f};
  const f32x4 kZero = {0.f, 0.f, 0.f, 0.f};

  auto stage = [&](int buf, int j0) {
    // F sub-tile: 16 KB contiguous in the global image (j0 multiple of 128)
    const uint4* srcF = (const uint4*)(F8 + ((size_t)(j0 >> 7) << 14));
#pragma unroll
    for (int k = 0; k < 4; ++k) {
      int off = ((k * 4 + wave) << 6) + lane;   // 16B-chunk idx 0..1023
      __builtin_amdgcn_global_load_lds(
          (const __attribute__((address_space(1))) uint4*)(srcF + off),
          (__attribute__((address_space(3))) uint4*)((uint4*)Fs[buf] + off), 16, 0, 0);
    }
    // V: 4 pair-groups = 256 uint4
    const uint4* srcV = (const uint4*)VF + ((size_t)(j0 >> 5) << 6);
    __builtin_amdgcn_global_load_lds(
        (const __attribute__((address_space(1))) uint4*)(srcV + t),
        (__attribute__((address_space(3))) uint4*)(Vs4[buf] + t), 16, 0, 0);
  };

  auto compute = [&](int buf) {
    const u8* fsb = Fs[buf];
    const uint4* vsb = Vs4[buf];
#pragma unroll
    for (int jp = 0; jp < BJ / 32; ++jp) {   // pairs of 16-row j-chunks
      union { uint4 h[2]; i32x8 v; } afe, afo;
      const u8* re = fsb + (jp * 32 + r) * 128;       // even chunk row
      const u8* ro = re + 16 * 128;                   // odd chunk row
      int c0 = (((2 * q) ^ (r & 7)) & 7) << 4;
      int c1 = (((2 * q + 1) ^ (r & 7)) & 7) << 4;
      afe.h[0] = *(const uint4*)(re + c0);
      afe.h[1] = *(const uint4*)(re + c1);
      afo.h[0] = *(const uint4*)(ro + c0);
      afo.h[1] = *(const uint4*)(ro + c1);
      union { uint4 qd; f16x8 v; } bv;
      bv.qd = vsb[jp * 64 + lane];
      // phase 1: all 8 QK MFMAs back-to-back (keeps the MFMA pipe fed)
      f32x4 ce[4], co[4];
#pragma unroll
      for (int s = 0; s < 4; ++s) {
        ce[s] = __builtin_amdgcn_mfma_scale_f32_16x16x128_f8f6f4(
            afe.v, bfr[s], kZero, 0, 0, 0, 0x7F7F7F7Fu, 0, 0x7F7F7F7Fu);
        co[s] = __builtin_amdgcn_mfma_scale_f32_16x16x128_f8f6f4(
            afo.v, bfr[s], kZero, 0, 0, 0, 0x7F7F7F7Fu, 0, 0x7F7F7F7Fu);
      }
      // phase 2: packs + PVs
#pragma unroll
      for (int s = 0; s < 4; ++s) {
        union { u32 u[4]; f16x8 v; } pf;
        pf.u[0] = packexp2f16(ce[s][0], ce[s][1]);
        pf.u[1] = packexp2f16(ce[s][2], ce[s][3]);
        pf.u[2] = packexp2f16(co[s][0], co[s][1]);
        pf.u[3] = packexp2f16(co[s][2], co[s][3]);
        acc[s] = __builtin_amdgcn_mfma_f32_16x16x32_f16(pf.v, bv.v, acc[s], 0, 0, 0);
      }
    }
  };

  // ---- double-buffered pipeline over the 8 tiles of this j-segment ----
  stage(0, jbase);
  __syncthreads();
#pragma unroll
  for (int jt = 0; jt < JSEG / BJ - 1; ++jt) {
    stage((jt + 1) & 1, jbase + (jt + 1) * BJ);  // prefetch overlaps compute
    compute(jt & 1);
    __syncthreads();  // drain waits on loads that ran under compute
  }
  compute((JSEG / BJ - 1) & 1);

  // acc[s] lane(q,r) reg rg = partial[row = i0+s*16+q*4+rg][col = r]
  if (r < 11) {
#pragma unroll
    for (int s = 0; s < 4; ++s) {
      float* op = P12 + (size_t)(i0 + s * 16 + q * 4) * VW + r;
      atomicAdd(&op[0 * VW], acc[s][0]);
      atomicAdd(&op[1 * VW], acc[s][1]);
      atomicAdd(&op[2 * VW], acc[s][2]);
      atomicAdd(&op[3 * VW], acc[s][3]);
    }
  }
}

// ---------------- finalize: class-count reduce + divides ----------------
__global__ void kfinal(float* __restrict__ out, const float* __restrict__ P12,
                       const float* __restrict__ clsPart) {
  __shared__ float clsS[16];
  int t = threadIdx.x;
  if (t < 64) {
    const float4* cp = (const float4*)clsPart;  // 64 rows x 4 float4
    float4 c0 = cp[t * 4], c1 = cp[t * 4 + 1], c2 = cp[t * 4 + 2], c3 = cp[t * 4 + 3];
#pragma unroll
    for (int off = 32; off >= 1; off >>= 1) {
      c0.x += __shfl_xor(c0.x, off); c0.y += __shfl_xor(c0.y, off);
      c0.z += __shfl_xor(c0.z, off); c0.w += __shfl_xor(c0.w, off);
      c1.x += __shfl_xor(c1.x, off); c1.y += __shfl_xor(c1.y, off);
      c1.z += __shfl_xor(c1.z, off); c1.w += __shfl_xor(c1.w, off);
      c2.x += __shfl_xor(c2.x, off); c2.y += __shfl_xor(c2.y, off);
    }
    if (t == 0) {
      *(float4*)&clsS[0] = c0;
      *(float4*)&clsS[4] = c1;
      clsS[8] = c2.x; clsS[9] = c2.y;
      clsS[10] = 0.f; clsS[11] = 0.f; clsS[12] = 0.f;
      clsS[13] = 0.f; clsS[14] = 0.f; clsS[15] = 0.f;
    }
  }
  __syncthreads();
  float d[NC]; float tot = 0.0f;
#pragma unroll
  for (int c = 0; c < NC; ++c) { d[c] = clsS[c]; tot += d[c]; }
  int row = blockIdx.x * 256 + t;  // 64 blocks x 256
  const float* pr = P12 + (size_t)row * VW;
  float rs = 1.0f / pr[10];
  float* op = out + (size_t)row * NC;
#pragma unroll
  for (int c = 0; c < NC; ++c) {
    float den = (d[c] == 0.0f) ? tot : d[c];
    op[c] = pr[c] * rs / den;
  }
}

extern "C" void kernel_launch(void* const* d_in, const int* in_sizes, int n_in,
                              void* d_out, int out_size, void* d_ws, size_t ws_size,
                              hipStream_t stream) {
  const float* anchor   = (const float*)d_in[0];  // 6144x128
  const float* positive = (const float*)d_in[1];  // 6144x128
  const float* lbfeat   = (const float*)d_in[2];  // 4096x128
  const float* onehot   = (const float*)d_in[3];  // 4096x10
  const float* l1       = (const float*)d_in[4];  // 6144x10
  const float* l2       = (const float*)d_in[5];  // 6144x10
  float* out = (float*)d_out;                     // 16384x10

  char* ws = (char*)d_ws;
  u8*     F8      = (u8*)ws;                                   // 2 MiB fp8 swizzled image
  f16_t*  VF      = (f16_t*)(ws + 2097152);                    // 512 KiB f16 pair-frags
  float*  P12     = (float*)(ws + 2097152 + 524288);           // 768 KiB
  float*  clsPart = (float*)(ws + 2097152 + 524288 + 786432);  // 4 KiB

  kprep2<<<1088, 256, 0, stream>>>(lbfeat, anchor, positive, onehot, l1, l2,
                                   F8, VF, clsPart, P12);
  kattn<<<dim3(NROWS / BI, SEG), 256, 0, stream>>>(F8, VF, P12);
  kfinal<<<NROWS / 256, 256, 0, stream>>>(out, P12, clsPart);
}